// Round 1
// baseline (464.625 us; speedup 1.0000x reference)
//
#include <hip/hip_runtime.h>
#include <hip/hip_fp16.h>

// DySample fused kernel for MI355X (gfx950) — round 4.
// x: [16,64,128,128] f32, w_off: [32,64] f32, b_off: [32] f32
// out: [16,64,256,256] f32
//
// r3 was gather-bound: 512 scalar global taps/thread, address-divergent,
// thrashing L1 at 64-VGPR occupancy. r4 stages a 10x34 halo window per
// (block, group, channel) in LDS (double-buffered, one barrier/channel),
// precomputes the 8 sample positions once per thread, and takes the 4
// bilinear taps as two ds_read2_b32 pairs from LDS. Generic global-gather
// fallback branch (per-lane `valid`) preserves correctness for large
// offsets; never taken for this input (|off| <= ~0.27).
// Stores: float4 NT (4 adjacent output cols per thread).

namespace {
constexpr int CC = 64;
constexpr int HH = 128;
constexpr int WW = 128;
constexpr int HW = HH * WW;     // 16384
constexpr int OW = 2 * WW;      // 256
constexpr int OHW = 4 * HW;     // 65536
constexpr int TH = 8, TW = 32;  // input tile (256 px)
// sampling halo window: rows th0-1..th0+8 (10), cols tw0-1..tw0+32 (34)
constexpr int WR = 10, WC = 34, WS = 36;   // WS = padded row stride
constexpr int WPLANE = WR * WS;            // 360 floats per plane
constexpr int WELEMS = WR * WC;            // 340 valid elems per plane
typedef float vfloat4 __attribute__((ext_vector_type(4)));
}

__global__ __launch_bounds__(256, 8)
void dysample_kernel(const float* __restrict__ x,
                     const float* __restrict__ w_off,
                     const float* __restrict__ b_off,
                     float* __restrict__ out) {
    __shared__ __half2 offh[8][256];        // 8 KB: (offx,offy) per local-q per pixel
    __shared__ float win[2][2][WPLANE];     // 5.76 KB: [buf][plane][r*WS+c]

    const int tid = threadIdx.x;
    const int gg   = blockIdx.x & 1;          // g-pair: g in {2gg, 2gg+1}
    const int tile = (blockIdx.x >> 1) & 63;
    const int b    = blockIdx.x >> 7;
    const int th0  = (tile >> 2) * TH;
    const int tw0  = (tile & 3) * TW;

    // ---------- Phase 1: 1x1 conv, 16 of 32 outputs at this thread's pixel ----
    // (verbatim from the verified r3 kernel)
    {
        const int ty = tid >> 5;              // [0,8)
        const int tx = tid & 31;              // [0,32)
        const int h  = th0 + ty;
        const int w  = tw0 + tx;
        const int q0 = gg * 8;

        float accx[8], accy[8];
#pragma unroll
        for (int j = 0; j < 8; ++j) {
            accx[j] = b_off[q0 + j];
            accy[j] = b_off[q0 + j + 16];
        }

        const float* xb = x + b * (CC * HW) + h * WW + w;
#pragma unroll
        for (int chunk = 0; chunk < 4; ++chunk) {
            float xv[16];
#pragma unroll
            for (int c = 0; c < 16; ++c) xv[c] = xb[(chunk * 16 + c) * HW];
#pragma unroll
            for (int j = 0; j < 8; ++j) {
                float ax = accx[j], ay = accy[j];
                const float* wx_ = w_off + (q0 + j) * 64 + chunk * 16;
                const float* wy_ = wx_ + 16 * 64;
#pragma unroll
                for (int c = 0; c < 16; ++c) ax = fmaf(xv[c], wx_[c], ax);
#pragma unroll
                for (int c = 0; c < 16; ++c) ay = fmaf(xv[c], wy_[c], ay);
                accx[j] = ax; accy[j] = ay;
            }
        }

#pragma unroll
        for (int j = 0; j < 8; ++j) {
            const int q = q0 + j, g = q >> 2, r1_ = (q >> 1) & 1, r2_ = q & 1;
            const float init = (((g & 1) ? r1_ : r2_) ? 0.25f : -0.25f);
            const float offx = fmaf(accx[j], 0.25f, init);
            const float offy = fmaf(accy[j], 0.25f, init);
            offh[j][tid] = __floats2half2_rn(offx, offy);
        }
    }
    __syncthreads();

    // ---------- Phase 2 setup: 8 sample positions per thread, computed once --
    // Thread -> output block: row oy (of 16), cols [4*ox4, 4*ox4+4) (of 64).
    const int oy  = tid >> 4;                 // [0,16)
    const int ox4 = tid & 15;                 // [0,16)
    const int hl  = oy >> 1;                  // local input row
    const int r1  = oy & 1;

    float wxv[8], wyv[8];
    int aidx[8];
    bool valid = true;
#pragma unroll
    for (int gi = 0; gi < 2; ++gi) {
#pragma unroll
        for (int pp = 0; pp < 4; ++pp) {
            const int s8 = gi * 4 + pp;
            const int wl = 2 * ox4 + (pp >> 1);           // local input col
            const int j  = gi * 4 + (r1 << 1) + (pp & 1); // local q
            const float2 o = __half22float2(offh[j][hl * 32 + wl]);
            float ix = ((float)(tw0 + wl) + 0.5f + o.x) - 0.5f;
            float iy = ((float)(th0 + hl) + 0.5f + o.y) - 0.5f;
            ix = fminf(fmaxf(ix, 0.0f), 127.0f);
            iy = fminf(fmaxf(iy, 0.0f), 127.0f);
            const float x0f = floorf(ix), y0f = floorf(iy);
            wxv[s8] = ix - x0f;
            wyv[s8] = iy - y0f;
            const int wi = (int)x0f - (tw0 - 1);   // window col of tap x0
            const int ri = (int)y0f - (th0 - 1);   // window row of tap y0
            valid = valid && ((unsigned)wi <= 32u) && ((unsigned)ri <= 8u);
            aidx[s8] = ri * WS + wi;
        }
    }

    // ---------- Staging descriptors: 680 halo floats / 256 threads -----------
    const float* xbase = x + (size_t)(b * CC + gg * 32) * HW;
    int soff0 = 0, soff1 = 0, soff2 = 0, dst0 = 0, dst1 = 0, dst2 = 0;
#pragma unroll
    for (int k = 0; k < 3; ++k) {
        const int e = tid + 256 * k;
        const int p = (e >= WELEMS) ? 1 : 0;
        const int rem = e - WELEMS * p;       // garbage for k=2, tid>=168 (guarded)
        const int r  = rem / WC;              // const-divisor -> magic mul
        const int jc = rem - r * WC;
        const int gr = min(max(th0 - 1 + r, 0), HH - 1);
        const int gc = min(max(tw0 - 1 + jc, 0), WW - 1);
        const int so = p * 16 * HW + gr * WW + gc;
        const int di = p * WPLANE + r * WS + jc;
        if (k == 0)      { soff0 = so; dst0 = di; }
        else if (k == 1) { soff1 = so; dst1 = di; }
        else             { soff2 = so; dst2 = di; }
    }
    const bool has2 = (tid < 2 * WELEMS - 512);   // tid < 168
    float* const winf = &win[0][0][0];
    float* const ob0 = out + (size_t)(b * CC + gg * 32) * OHW
                     + (size_t)(2 * th0 + oy) * OW + 2 * tw0 + 4 * ox4;

    // prologue: stage channel 0 into buf 0
    {
        const float s0 = xbase[soff0];
        const float s1 = xbase[soff1];
        float s2 = 0.0f;
        if (has2) s2 = xbase[soff2];
        winf[dst0] = s0;
        winf[dst1] = s1;
        if (has2) winf[dst2] = s2;
        soff0 += HW; soff1 += HW; soff2 += HW;
    }
    __syncthreads();

    // ---------- Phase 3: per-channel sample (double-buffered windows) --------
#pragma unroll 2
    for (int c = 0; c < 16; ++c) {
        const int buf = c & 1;
        const bool more = (c < 15);
        float s0 = 0.0f, s1 = 0.0f, s2 = 0.0f;
        if (more) {                           // issue next-channel loads early
            s0 = xbase[soff0];
            s1 = xbase[soff1];
            if (has2) s2 = xbase[soff2];
            soff0 += HW; soff1 += HW; soff2 += HW;
        }

        const float* Wb = winf + buf * (2 * WPLANE);
        if (valid) {
#pragma unroll
            for (int gi = 0; gi < 2; ++gi) {
                const float* Wp = Wb + gi * WPLANE;
                vfloat4 res;
#pragma unroll
                for (int pp = 0; pp < 4; ++pp) {
                    const int s8 = gi * 4 + pp;
                    const int a = aidx[s8];
                    const float t00 = Wp[a],      t01 = Wp[a + 1];
                    const float t10 = Wp[a + WS], t11 = Wp[a + WS + 1];
                    const float hh0 = fmaf(wxv[s8], t01 - t00, t00);
                    const float hh1 = fmaf(wxv[s8], t11 - t10, t10);
                    res[pp] = fmaf(wyv[s8], hh1 - hh0, hh0);
                }
                __builtin_nontemporal_store(
                    res, (vfloat4*)(ob0 + (size_t)(gi * 16 + c) * OHW));
            }
        } else {
            // Generic fallback: global gather with border clamp (never taken
            // for this input; execz-skipped). Keeps arbitrary offsets correct.
#pragma unroll
            for (int gi = 0; gi < 2; ++gi) {
                vfloat4 res;
#pragma unroll
                for (int pp = 0; pp < 4; ++pp) {
                    const int wl = 2 * ox4 + (pp >> 1);
                    const int j  = gi * 4 + (r1 << 1) + (pp & 1);
                    const float2 o = __half22float2(offh[j][hl * 32 + wl]);
                    float ix = ((float)(tw0 + wl) + 0.5f + o.x) - 0.5f;
                    float iy = ((float)(th0 + hl) + 0.5f + o.y) - 0.5f;
                    ix = fminf(fmaxf(ix, 0.0f), 127.0f);
                    iy = fminf(fmaxf(iy, 0.0f), 127.0f);
                    const float x0f = floorf(ix), y0f = floorf(iy);
                    const float wx = ix - x0f, wy = iy - y0f;
                    const int xa = (int)x0f, ya = (int)y0f;
                    const int xb2 = min(xa + 1, WW - 1);
                    const int yb2 = min(ya + 1, HH - 1);
                    const float* xs = xbase + (size_t)(gi * 16 + c) * HW;
                    const float v00 = xs[ya * WW + xa],  v01 = xs[ya * WW + xb2];
                    const float v10 = xs[yb2 * WW + xa], v11 = xs[yb2 * WW + xb2];
                    const float hh0 = fmaf(wx, v01 - v00, v00);
                    const float hh1 = fmaf(wx, v11 - v10, v10);
                    res[pp] = fmaf(wy, hh1 - hh0, hh0);
                }
                __builtin_nontemporal_store(
                    res, (vfloat4*)(ob0 + (size_t)(gi * 16 + c) * OHW));
            }
        }

        if (more) {                           // write staged channel c+1
            float* Wn = winf + (buf ^ 1) * (2 * WPLANE);
            Wn[dst0] = s0;
            Wn[dst1] = s1;
            if (has2) Wn[dst2] = s2;
        }
        __syncthreads();
    }
}

extern "C" void kernel_launch(void* const* d_in, const int* in_sizes, int n_in,
                              void* d_out, int out_size, void* d_ws, size_t ws_size,
                              hipStream_t stream) {
    const float* x     = (const float*)d_in[0];
    const float* w_off = (const float*)d_in[1];
    const float* b_off = (const float*)d_in[2];
    float* out = (float*)d_out;
    (void)in_sizes; (void)n_in; (void)out_size; (void)d_ws; (void)ws_size;
    dysample_kernel<<<dim3(16 * 64 * 2), dim3(256), 0, stream>>>(x, w_off, b_off, out);
}